// Round 5
// baseline (113.609 us; speedup 1.0000x reference)
//
#include <hip/hip_runtime.h>
#include <math.h>

// Problem geometry (fixed): B=8, C=4, H=W=256; 24 = B*3 slices per mask type.
#define HWTOT 65536
#define WD 256
#define HT 256
#define NSL 24

// Workspace layout (bytes) — everything written before read; no memset needed.
static constexpr size_t OFF_CNT  = 0;                         // 48 ints
static constexpr size_t OFF_PART = 256;                       // 6144 f32 -> ends 24832
static constexpr size_t OFF_MASK = 24832;                     // 24*65536 u8 (bit0=P, bit1=T)
static constexpr size_t OFF_ERR  = OFF_MASK + (size_t)NSL * HWTOT;      // f16
static constexpr size_t OFF_BITS = OFF_ERR + (size_t)NSL * HWTOT * 2;   // u32[2][24][8][256]
// Column bitmaps: bit r of bits[f][s][k][w] = mask bit f at (row 32k+r, col w).

// ---------------- Kernel 1: masks + err ----------------
__global__ __launch_bounds__(256) void k_mask(
    const float* __restrict__ pS, const float* __restrict__ pT,
    unsigned char* __restrict__ mask, _Float16* __restrict__ err)
{
    int blk = blockIdx.x;
    int b   = blk >> 8;          // image 0..7
    int hw  = (blk & 255) * 256 + threadIdx.x;

    const float* ps = pS + (size_t)b * 4 * HWTOT + hw;
    float s0 = ps[0], s1 = ps[HWTOT], s2 = ps[2 * HWTOT], s3 = ps[3 * HWTOT];
    float mx = fmaxf(fmaxf(s0, s1), fmaxf(s2, s3));
    float e0 = expf(s0 - mx), e1 = expf(s1 - mx), e2 = expf(s2 - mx), e3 = expf(s3 - mx);
    float inv = 1.0f / (e0 + e1 + e2 + e3);

    const float* pt = pT + (size_t)b * 4 * HWTOT + hw;
    float t0 = pt[0], t1 = pt[HWTOT], t2 = pt[2 * HWTOT], t3 = pt[3 * HWTOT];
    int lab = 0; float bm = t0;
    if (t1 > bm) { bm = t1; lab = 1; }
    if (t2 > bm) { bm = t2; lab = 2; }
    if (t3 > bm) { bm = t3; lab = 3; }

    float pv[3] = { e1 * inv, e2 * inv, e3 * inv };
    #pragma unroll
    for (int cc = 0; cc < 3; ++cc) {
        int sl = b * 3 + cc;
        bool mp = pv[cc] > 0.5f;
        bool mt = (lab == cc + 1);
        mask[(size_t)sl * HWTOT + hw] = (unsigned char)((mp ? 1 : 0) | (mt ? 2 : 0));
        float tcv = mt ? 1.0f : 0.0f;
        float ev = (pv[cc] - tcv) * (pv[cc] - tcv);
        err[(size_t)sl * HWTOT + hw] = (_Float16)ev;
    }
}

// ---------------- Kernel 2: pack columns into bitmaps + counts ----------------
// Block = slice. Thread = column. Loads coalesced (row-major), builds 8 words
// per field in scalars (no arrays), popcount block-reduce -> cnts plain store.
__global__ __launch_bounds__(256) void k_pack(
    const unsigned char* __restrict__ mask, unsigned* __restrict__ bits,
    int* __restrict__ cnts)
{
    int s = blockIdx.x;
    int w = threadIdx.x;
    const unsigned char* m = mask + (size_t)s * HWTOT + w;

    int cp = 0, ct = 0;
    #pragma unroll
    for (int k = 0; k < 8; ++k) {
        unsigned vp = 0, vt = 0;
        #pragma unroll
        for (int i = 0; i < 32; ++i) {
            unsigned v = m[(k * 32 + i) * WD];
            vp |= (v & 1u) << i;
            vt |= ((v >> 1) & 1u) << i;
        }
        bits[((size_t)(0 * NSL + s) * 8 + k) * WD + w] = vp;
        bits[((size_t)(1 * NSL + s) * 8 + k) * WD + w] = vt;
        cp += __popc(vp); ct += __popc(vt);
    }

    __shared__ int redc[8];
    #pragma unroll
    for (int i = 1; i < 64; i <<= 1) { cp += __shfl_xor(cp, i); ct += __shfl_xor(ct, i); }
    if ((w & 63) == 0) { redc[w >> 6] = cp; redc[4 + (w >> 6)] = ct; }
    __syncthreads();
    if (w == 0) cnts[s]       = redc[0] + redc[1] + redc[2] + redc[3];
    if (w == 1) cnts[NSL + s] = redc[4] + redc[5] + redc[6] + redc[7];
}

// Branch-free vertical distance from column bitmap (statically indexed words).
// Returns distance (>=1) to nearest bit differing from `inv`-encoded own bit,
// 512 if none. h is block-uniform.
__device__ __forceinline__ int vdist(const unsigned W[8], unsigned inv, int h)
{
    int dd = 512;
    #pragma unroll
    for (int k = 0; k < 8; ++k) {           // ascending: first hit = nearest below
        unsigned y = W[k] ^ inv;
        unsigned gate;
        if (k * 32 + 31 <= h)      gate = 0u;
        else if (k * 32 > h)       gate = 0xFFFFFFFFu;
        else                       gate = 0xFFFFFFFFu << ((h - k * 32) + 1);
        unsigned z = y & gate;
        int cand = k * 32 + (__ffs(z) - 1) - h;
        dd = (z && dd == 512) ? cand : dd;
    }
    int du = 512;
    #pragma unroll
    for (int k = 7; k >= 0; --k) {          // descending: first hit = nearest above
        unsigned y = W[k] ^ inv;
        unsigned gate;
        if (k * 32 >= h)           gate = 0u;
        else if (k * 32 + 32 <= h) gate = 0xFFFFFFFFu;
        else                       gate = (1u << (h - k * 32)) - 1u;
        unsigned z = y & gate;
        int cand = h - (k * 32 + 31 - __clz(z));
        du = (z && du == 512) ? cand : du;
    }
    return min(dd, du);
}

// ---------------- Kernel 3: vertical-from-bitmap + horizontal min + loss ------
__global__ __launch_bounds__(256) void k_row(
    const _Float16* __restrict__ err, const unsigned* __restrict__ bits,
    const int* __restrict__ cnts, float* __restrict__ partials)
{
    int h  = blockIdx.x;        // row 0..255
    int s  = blockIdx.y;        // slice 0..23
    int jo = threadIdx.x;

    __shared__ float4 g2[768];
    __shared__ float  wred[4];

    const unsigned* bP = bits + (size_t)(0 * NSL + s) * 8 * WD;
    const unsigned* bT = bits + (size_t)(1 * NSL + s) * 8 * WD;
    unsigned WP[8], WT[8];
    #pragma unroll
    for (int k = 0; k < 8; ++k) { WP[k] = bP[k * WD + jo]; WT[k] = bT[k * WD + jo]; }

    int kh = h >> 5, r = h & 31;
    unsigned mywP = 0, mywT = 0;
    #pragma unroll
    for (int k = 0; k < 8; ++k) if (k == kh) { mywP = WP[k]; mywT = WT[k]; }
    bool selP = (mywP >> r) & 1;
    bool selT = (mywT >> r) & 1;

    int gcP = vdist(WP, selP ? 0xFFFFFFFFu : 0u, h);
    int gcT = vdist(WT, selT ? 0xFFFFFFFFu : 0u, h);

    int cp = cnts[s];
    int ct = cnts[NSL + s];
    bool validP = (cp > 0) && (cp < HWTOT);
    bool validT = (ct > 0) && (ct < HWTOT);

    float fP = (float)(gcP * gcP);
    float fT = (float)(gcT * gcT);
    g2[256 + jo] = make_float4(selP ? fP : 0.0f, selP ? 0.0f : fP,
                               selT ? fT : 0.0f, selT ? 0.0f : fT);
    float4 inf4 = make_float4(1e30f, 1e30f, 1e30f, 1e30f);
    g2[jo] = inf4;
    g2[512 + jo] = inf4;

    int gsp = validP ? gcP : 0;
    int gst = validT ? gcT : 0;
    int R = min(max(gsp, gst), 256);
    #pragma unroll
    for (int i = 1; i < 64; i <<= 1) R = max(R, __shfl_xor(R, i));

    float m1 = (float)(gsp * gsp);
    float m2 = (float)(gst * gst);
    __syncthreads();

    for (int dd = 1; dd < R; ++dd) {
        float4 L  = g2[256 + jo - dd];
        float4 Rv = g2[256 + jo + dd];
        float d2 = (float)(dd * dd);
        float c1 = fminf(selP ? L.x : L.y, selP ? Rv.x : Rv.y);
        float c2 = fminf(selT ? L.z : L.w, selT ? Rv.z : Rv.w);
        m1 = fminf(m1, c1 + d2);
        m2 = fminf(m2, c2 + d2);
    }

    size_t rbase = (size_t)s * HWTOT + h * WD + jo;
    float contrib = (float)err[rbase] * (m1 + m2);

    #pragma unroll
    for (int off = 32; off > 0; off >>= 1) contrib += __shfl_down(contrib, off);
    if ((jo & 63) == 0) wred[jo >> 6] = contrib;
    __syncthreads();
    if (jo == 0) partials[s * 256 + h] = wred[0] + wred[1] + wred[2] + wred[3];
}

// ---------------- Kernel 4: final reduce (double) + log ----------------
__global__ __launch_bounds__(256) void k_final(
    const float* __restrict__ partials, float* __restrict__ out)
{
    __shared__ double red[256];
    int t = threadIdx.x;
    double acc = 0.0;
    for (int i = t; i < NSL * 256; i += 256) acc += (double)partials[i];
    red[t] = acc;
    __syncthreads();
    for (int off = 128; off > 0; off >>= 1) {
        if (t < off) red[t] += red[t + off];
        __syncthreads();
    }
    if (t == 0) {
        double loss = red[0] / (double)((size_t)NSL * HWTOT);
        out[0] = (float)log(loss + 1.0);
    }
}

extern "C" void kernel_launch(void* const* d_in, const int* in_sizes, int n_in,
                              void* d_out, int out_size, void* d_ws, size_t ws_size,
                              hipStream_t stream)
{
    const float* pS = (const float*)d_in[0];
    const float* pT = (const float*)d_in[1];
    float* out = (float*)d_out;

    char* ws = (char*)d_ws;
    int*            cnts  = (int*)(ws + OFF_CNT);
    float*          parts = (float*)(ws + OFF_PART);
    unsigned char*  mask  = (unsigned char*)(ws + OFF_MASK);
    _Float16*       err   = (_Float16*)(ws + OFF_ERR);
    unsigned*       bits  = (unsigned*)(ws + OFF_BITS);

    k_mask <<<dim3(2048),     dim3(256), 0, stream>>>(pS, pT, mask, err);
    k_pack <<<dim3(NSL),      dim3(256), 0, stream>>>(mask, bits, cnts);
    k_row  <<<dim3(256, NSL), dim3(256), 0, stream>>>(err, bits, cnts, parts);
    k_final<<<dim3(1),        dim3(256), 0, stream>>>(parts, out);
}